// Round 1
// baseline (707.693 us; speedup 1.0000x reference)
//
#include <hip/hip_runtime.h>
#include <hip/hip_bf16.h>
#include <math.h>

// Problem constants
#define HH 80
#define WW 80
#define NPIX 6400          // H*W
#define CC 36              // 6 labels x 6 channels, batched
#define NC 6
#define NUM_ITER 5
#define JS 16              // j-slices for bilateral pass
#define SLICE (NPIX / JS)  // 400
#define TJ 100             // j-tile staged in LDS
#define CHUNKS (SLICE / TJ)

// exp2 coefficients: exp(-d/(2*theta^2)) = exp2(C*d)
// Ca: spatial bilateral (theta_alpha=8  -> 2*64   = 128)
// Cb: feature bilateral (theta_beta=.15 -> 2*.0225= 0.045)
// Cg: spatial-only      (theta_gamma=3  -> 2*9    = 18)
__device__ __constant__ const float kCa = (float)(-1.0 / (128.0  * 0.6931471805599453));
__device__ __constant__ const float kCb = (float)(-1.0 / (0.045  * 0.6931471805599453));
__device__ __constant__ const float kCg = (float)(-1.0 / (18.0   * 0.6931471805599453));

// ---------------------------------------------------------------------------
// init: q[n][l*6+c] = unary[n][c]; norm_s[n] = analytic separable row-sum
// ---------------------------------------------------------------------------
__global__ __launch_bounds__(256) void k_init(const float* __restrict__ unary,
                                              float* __restrict__ q,
                                              float* __restrict__ norm_s) {
    int i = blockIdx.x * 256 + threadIdx.x;
    if (i >= NPIX) return;
    int y = i / WW, x = i - y * WW;
    float Sy = 0.f, Sx = 0.f;
    for (int t = 0; t < 80; t++) {
        float dy = (float)(y - t), dx = (float)(x - t);
        Sy += exp2f(kCg * dy * dy);
        Sx += exp2f(kCg * dx * dx);
    }
    norm_s[i] = Sy * Sx;
    float u[NC];
#pragma unroll
    for (int c = 0; c < NC; c++) u[c] = unary[i * NC + c];
#pragma unroll
    for (int l = 0; l < NC; l++)
#pragma unroll
        for (int c = 0; c < NC; c++) q[i * CC + l * NC + c] = u[c];
}

// ---------------------------------------------------------------------------
// softmax over channels for each (pixel, label)
// ---------------------------------------------------------------------------
__global__ __launch_bounds__(256) void k_softmax(const float* __restrict__ q,
                                                 float* __restrict__ sm) {
    int t = blockIdx.x * 256 + threadIdx.x;  // t = n*6 + l
    if (t >= NPIX * NC) return;
    const float* qp = q + (size_t)t * NC;
    float v[NC], mx = -1e30f;
#pragma unroll
    for (int c = 0; c < NC; c++) { v[c] = qp[c]; mx = fmaxf(mx, v[c]); }
    float sum = 0.f;
#pragma unroll
    for (int c = 0; c < NC; c++) { v[c] = __expf(v[c] - mx); sum += v[c]; }
    float inv = 1.f / sum;
    float* sp = sm + (size_t)t * NC;
#pragma unroll
    for (int c = 0; c < NC; c++) sp[c] = v[c] * inv;
}

// ---------------------------------------------------------------------------
// bilateral N^2 pass: part_b[s][i][cc] = sum_{j in slice s} w(i,j)*sm[j][cc]
// WITH_NORM also accumulates part_nb[s][i] = sum w(i,j)
// ---------------------------------------------------------------------------
template <bool WITH_NORM>
__global__ __launch_bounds__(256) void k_bilateral(const float* __restrict__ sm,
                                                   const float* __restrict__ feat,
                                                   float* __restrict__ part_b,
                                                   float* __restrict__ part_nb) {
    __shared__ __align__(16) float s_sm[TJ * CC];
    __shared__ __align__(16) float s_ft[TJ * 3];
    int tid = threadIdx.x;
    int i = blockIdx.x * 256 + tid;  // pixel i, 0..6399
    int s = blockIdx.y;              // j-slice

    int yi_i = i / WW;
    float yi = (float)yi_i;
    float xi = (float)(i - yi_i * WW);
    float fi0 = feat[i * 3 + 0], fi1 = feat[i * 3 + 1], fi2 = feat[i * 3 + 2];

    float4 acc[9];
#pragma unroll
    for (int r = 0; r < 9; r++) acc[r] = make_float4(0.f, 0.f, 0.f, 0.f);
    float wsum = 0.f;

    for (int ch = 0; ch < CHUNKS; ch++) {
        int jbase = s * SLICE + ch * TJ;
        __syncthreads();  // protect LDS from previous chunk readers
        {   // stage sm tile: TJ*CC floats, contiguous
            const float4* src = (const float4*)(sm + (size_t)jbase * CC);
            float4* dst = (float4*)s_sm;
            for (int idx = tid; idx < TJ * CC / 4; idx += 256) dst[idx] = src[idx];
            const float4* fsrc = (const float4*)(feat + (size_t)jbase * 3);
            float4* fdst = (float4*)s_ft;
            for (int idx = tid; idx < TJ * 3 / 4; idx += 256) fdst[idx] = fsrc[idx];
        }
        __syncthreads();

        for (int jj = 0; jj < TJ; jj++) {
            int j = jbase + jj;
            int yj_i = j / WW;
            float yj = (float)yj_i;
            float xj = (float)(j - yj_i * WW);
            float dy = yi - yj, dx = xi - xj;
            float f0 = s_ft[jj * 3 + 0], f1 = s_ft[jj * 3 + 1], f2 = s_ft[jj * 3 + 2];
            float d0 = fi0 - f0, d1 = fi1 - f1, d2 = fi2 - f2;
            float arg = kCa * (dy * dy + dx * dx) + kCb * (d0 * d0 + d1 * d1 + d2 * d2);
            float w = exp2f(arg);
            if (WITH_NORM) wsum += w;
            const float4* smj = (const float4*)(s_sm + jj * CC);
#pragma unroll
            for (int r = 0; r < 9; r++) {
                float4 v = smj[r];
                acc[r].x = fmaf(w, v.x, acc[r].x);
                acc[r].y = fmaf(w, v.y, acc[r].y);
                acc[r].z = fmaf(w, v.z, acc[r].z);
                acc[r].w = fmaf(w, v.w, acc[r].w);
            }
        }
    }
    float4* outp = (float4*)(part_b + ((size_t)s * NPIX + i) * CC);
#pragma unroll
    for (int r = 0; r < 9; r++) outp[r] = acc[r];
    if (WITH_NORM) part_nb[s * NPIX + i] = wsum;
}

__global__ __launch_bounds__(256) void k_reduce_norm(const float* __restrict__ part_nb,
                                                     float* __restrict__ norm_b) {
    int i = blockIdx.x * 256 + threadIdx.x;
    if (i >= NPIX) return;
    float s = 0.f;
    for (int sl = 0; sl < JS; sl++) s += part_nb[sl * NPIX + i];
    norm_b[i] = s;
}

// ---------------------------------------------------------------------------
// exact separable spatial filter (two 80-tap passes)
// ---------------------------------------------------------------------------
__global__ __launch_bounds__(256) void k_convx(const float* __restrict__ in,
                                               float* __restrict__ out) {
    __shared__ float g[80];
    int tid = threadIdx.x;
    if (tid < 80) { float d = (float)tid; g[tid] = exp2f(kCg * d * d); }
    __syncthreads();
    int t = blockIdx.x * 256 + tid;  // over NPIX*CC
    if (t >= NPIX * CC) return;
    int cc = t % CC;
    int x = (t / CC) % WW;
    int y = t / (CC * WW);
    const float* row = in + (size_t)(y * WW) * CC + cc;
    float acc = 0.f;
    for (int xp = 0; xp < WW; xp++) acc = fmaf(g[abs(x - xp)], row[(size_t)xp * CC], acc);
    out[t] = acc;
}

__global__ __launch_bounds__(256) void k_convy(const float* __restrict__ in,
                                               float* __restrict__ out) {
    __shared__ float g[80];
    int tid = threadIdx.x;
    if (tid < 80) { float d = (float)tid; g[tid] = exp2f(kCg * d * d); }
    __syncthreads();
    int t = blockIdx.x * 256 + tid;
    if (t >= NPIX * CC) return;
    int cc = t % CC;
    int x = (t / CC) % WW;
    int y = t / (CC * WW);
    float acc = 0.f;
    for (int yp = 0; yp < HH; yp++)
        acc = fmaf(g[abs(y - yp)], in[(size_t)(yp * WW + x) * CC + cc], acc);
    out[t] = acc;
}

// ---------------------------------------------------------------------------
// update: message, pairwise, q; stores msg for the ELBO
// ---------------------------------------------------------------------------
__global__ __launch_bounds__(256) void k_update(const float* __restrict__ part_b,
                                                const float* __restrict__ filt_s,
                                                const float* __restrict__ norm_s,
                                                const float* __restrict__ norm_b,
                                                const float* __restrict__ unary,
                                                const float* __restrict__ SW,
                                                const float* __restrict__ BW,
                                                const float* __restrict__ CM,
                                                const float* __restrict__ LG,
                                                float* __restrict__ q,
                                                float* __restrict__ msg) {
    __shared__ float sSW[36], sBW[36], sCM[36], sLG[36];
    int tid = threadIdx.x;
    if (tid < 36) { sSW[tid] = SW[tid]; sBW[tid] = BW[tid]; sCM[tid] = CM[tid]; sLG[tid] = LG[tid]; }
    __syncthreads();
    int t = blockIdx.x * 256 + tid;  // t = n*6 + l
    if (t >= NPIX * NC) return;
    int n = t / NC, l = t - n * NC;
    float invs = 1.f / norm_s[n];
    float invb = 1.f / norm_b[n];
    float fs[NC], fb[NC];
#pragma unroll
    for (int c = 0; c < NC; c++) fb[c] = 0.f;
    for (int s = 0; s < JS; s++) {
        const float* pp = part_b + ((size_t)s * NPIX + n) * CC + l * NC;
#pragma unroll
        for (int c = 0; c < NC; c++) fb[c] += pp[c];
    }
    const float* fsp = filt_s + (size_t)n * CC + l * NC;
#pragma unroll
    for (int c = 0; c < NC; c++) { fs[c] = fsp[c] * invs; fb[c] *= invb; }
    float m[NC];
#pragma unroll
    for (int c = 0; c < NC; c++) {
        float a = 0.f;
#pragma unroll
        for (int cp = 0; cp < NC; cp++)
            a += sSW[c * NC + cp] * fs[cp] + sBW[c * NC + cp] * fb[cp];
        m[c] = a;
    }
    float* mp = msg + (size_t)n * CC + l * NC;
#pragma unroll
    for (int c = 0; c < NC; c++) mp[c] = m[c];
    float* qp = q + (size_t)n * CC + l * NC;
    const float* up = unary + (size_t)n * NC;
#pragma unroll
    for (int c = 0; c < NC; c++) {
        float pw = 0.f;
#pragma unroll
        for (int cp = 0; cp < NC; cp++) pw += sCM[c * NC + cp] * m[cp];
        qp[c] = up[c] + sLG[c * NC + l] - pw;
    }
}

// ---------------------------------------------------------------------------
// ELBO: out[l] = sum_{n,c} sm*(unary + LG - ln(sm+1e-10) - msg)
// ---------------------------------------------------------------------------
__global__ __launch_bounds__(256) void k_elbo(const float* __restrict__ sm,
                                              const float* __restrict__ msg,
                                              const float* __restrict__ unary,
                                              const float* __restrict__ LG,
                                              float* __restrict__ out) {
    __shared__ float red[256];
    int l = blockIdx.y;
    int n = blockIdx.x * 256 + threadIdx.x;
    float v = 0.f;
    if (n < NPIX) {
        const float* sp = sm + (size_t)n * CC + l * NC;
        const float* mp = msg + (size_t)n * CC + l * NC;
        const float* up = unary + (size_t)n * NC;
#pragma unroll
        for (int c = 0; c < NC; c++) {
            float s = sp[c];
            v += s * (up[c] + LG[c * NC + l] - logf(s + 1e-10f) - mp[c]);
        }
    }
    red[threadIdx.x] = v;
    __syncthreads();
    for (int off = 128; off > 0; off >>= 1) {
        if (threadIdx.x < off) red[threadIdx.x] += red[threadIdx.x + off];
        __syncthreads();
    }
    if (threadIdx.x == 0) atomicAdd(&out[l], red[0]);
}

// ---------------------------------------------------------------------------
extern "C" void kernel_launch(void* const* d_in, const int* in_sizes, int n_in,
                              void* d_out, int out_size, void* d_ws, size_t ws_size,
                              hipStream_t stream) {
    const float* unary = (const float*)d_in[0];  // [N][6]
    const float* feat  = (const float*)d_in[1];  // [N][3]
    const float* CM    = (const float*)d_in[2];  // [6][6]
    const float* LG    = (const float*)d_in[3];
    const float* SW    = (const float*)d_in[4];
    const float* BW    = (const float*)d_in[5];
    float* out = (float*)d_out;

    float* ws = (float*)d_ws;
    float* norm_s  = ws;                      // N
    float* norm_b  = norm_s + NPIX;           // N
    float* q       = norm_b + NPIX;           // N*36
    float* sm      = q + (size_t)NPIX * CC;   // N*36
    float* tmpx    = sm + (size_t)NPIX * CC;  // N*36
    float* filt_s  = tmpx + (size_t)NPIX * CC;
    float* msg     = filt_s + (size_t)NPIX * CC;
    float* part_nb = msg + (size_t)NPIX * CC;          // JS*N
    float* part_b  = part_nb + (size_t)JS * NPIX;      // JS*N*36

    k_init<<<25, 256, 0, stream>>>(unary, q, norm_s);

    for (int it = 0; it < NUM_ITER; it++) {
        k_softmax<<<150, 256, 0, stream>>>(q, sm);
        if (it == 0) {
            k_bilateral<true><<<dim3(25, JS), 256, 0, stream>>>(sm, feat, part_b, part_nb);
            k_reduce_norm<<<25, 256, 0, stream>>>(part_nb, norm_b);
        } else {
            k_bilateral<false><<<dim3(25, JS), 256, 0, stream>>>(sm, feat, part_b, part_nb);
        }
        k_convx<<<900, 256, 0, stream>>>(sm, tmpx);
        k_convy<<<900, 256, 0, stream>>>(tmpx, filt_s);
        k_update<<<150, 256, 0, stream>>>(part_b, filt_s, norm_s, norm_b, unary,
                                          SW, BW, CM, LG, q, msg);
    }

    hipMemsetAsync(out, 0, out_size * sizeof(float), stream);
    k_elbo<<<dim3(25, NC), 256, 0, stream>>>(sm, msg, unary, LG, out);
}